// Round 2
// 184.554 us; speedup vs baseline: 1.0100x; 1.0100x over previous
//
#include <hip/hip_runtime.h>
#include <hip/hip_bf16.h>
#include <math.h>

// Problem constants
constexpr int B    = 4;
constexpr int D    = 768;
constexpr int HW   = 1024;
constexpr int M    = B * HW;        // 4096 queries
constexpr int NDB  = 20000;
constexpr int LT   = 158;           // 128-row layout tiles (20224 rows padded)
constexpr int NDBP = LT * 128;      // 20224
constexpr int OUTH = 512;
constexpr int OUTW = 512;

constexpr int BM     = 256;         // db rows per gemm tile (2 layout tiles)
constexpr int BN     = 128;         // queries per tile
constexpr int KSTEPS = D / 64;      // 12 64-K steps
constexpr int NSPLIT = 16;
constexpr int NT2    = 79;          // 256-row gemm tiles
constexpr int STEPB  = 128 * 64;    // 8192 B per 64-K step-block (one layout tile)

constexpr int ABUF = 16384;         // A bytes per K-step buffer
constexpr int BBUF = 8192;          // B bytes per K-step buffer

typedef int   i32x8  __attribute__((ext_vector_type(8)));
typedef float f32x16 __attribute__((ext_vector_type(16)));

__device__ __forceinline__ void insert3(float& t0, float& t1, float& t2, float d) {
    float a0 = fminf(d, t0);
    float b0 = fmaxf(d, t0);
    float a1 = fminf(b0, t1);
    float b1 = fmaxf(b0, t1);
    t0 = a0; t1 = a1;
    t2 = fminf(b1, t2);
}

__device__ __forceinline__ unsigned int pack4_fp8(float a, float b, float c, float d) {
    int v = __builtin_amdgcn_cvt_pk_fp8_f32(a, b, 0, false);
    v = __builtin_amdgcn_cvt_pk_fp8_f32(c, d, v, true);
    return (unsigned int)v;
}

__device__ __forceinline__ void gl_lds16(const unsigned char* g, unsigned char* l) {
    __builtin_amdgcn_global_load_lds(
        (const __attribute__((address_space(1))) void*)g,
        (__attribute__((address_space(3))) void*)l, 16, 0, 0);
}

// ---------------------------------------------------------------------------
// 1) db [20000][768] fp32 -> fp8 tiled [158][12][rg 4][h2 2][kc 2][r 32][16B]
__global__ __launch_bounds__(256) void db_convert(const float* __restrict__ db,
                                                  uint4* __restrict__ dbt8,
                                                  float* __restrict__ x2p) {
    __shared__ float panel[128][68];
    __shared__ float part[512];
    const int lt = blockIdx.x;
    const int g  = blockIdx.y;
    const int t  = threadIdx.x;
    const int n0 = lt * 128;

    #pragma unroll
    for (int pass = 0; pass < 8; ++pass) {
        int idx = pass * 256 + t;            // 0..2047
        int row = idx >> 4, c4 = idx & 15;
        int n = n0 + row;
        float4 v = make_float4(0.f, 0.f, 0.f, 0.f);
        if (n < NDB) v = *(const float4*)(db + (size_t)n * D + g * 64 + c4 * 4);
        *(float4*)&panel[row][c4 * 4] = v;
    }
    __syncthreads();
    #pragma unroll
    for (int pass = 0; pass < 2; ++pass) {
        int idx = pass * 256 + t;            // bits [rg:2][h2:1][kc:1][r:5]
        int r  = idx & 31;
        int kc = (idx >> 5) & 1;
        int h2 = (idx >> 6) & 1;
        int rg = idx >> 7;
        int row  = rg * 32 + r;
        int kloc = kc * 32 + h2 * 16;
        float4 va = *(const float4*)&panel[row][kloc + 0];
        float4 vb = *(const float4*)&panel[row][kloc + 4];
        float4 vc = *(const float4*)&panel[row][kloc + 8];
        float4 vd = *(const float4*)&panel[row][kloc + 12];
        float ss = va.x*va.x + va.y*va.y + va.z*va.z + va.w*va.w
                 + vb.x*vb.x + vb.y*vb.y + vb.z*vb.z + vb.w*vb.w
                 + vc.x*vc.x + vc.y*vc.y + vc.z*vc.z + vc.w*vc.w
                 + vd.x*vd.x + vd.y*vd.y + vd.z*vd.z + vd.w*vd.w;
        uint4 o;
        o.x = pack4_fp8(va.x, va.y, va.z, va.w);
        o.y = pack4_fp8(vb.x, vb.y, vb.z, vb.w);
        o.z = pack4_fp8(vc.x, vc.y, vc.z, vc.w);
        o.w = pack4_fp8(vd.x, vd.y, vd.z, vd.w);
        dbt8[((size_t)lt * KSTEPS + g) * 512 + idx] = o;
        part[idx] = ss;
    }
    __syncthreads();
    if (t < 128) {
        int base = (t >> 5) * 128 + (t & 31);
        float s = part[base] + part[base + 32] + part[base + 64] + part[base + 96];
        x2p[((size_t)lt * KSTEPS + g) * 128 + t] = s;
    }
}

// ---------------------------------------------------------------------------
// 2) emb [4][768][1024] -> fp8 (-2*q) tiled [32][12][rg][h2][kc][r][16B]
__global__ __launch_bounds__(256) void q_convert(const float* __restrict__ emb,
                                                 uint4* __restrict__ qbt8,
                                                 float* __restrict__ q2p) {
    __shared__ float part[512];
    const int qt = blockIdx.x;           // 0..31
    const int g  = blockIdx.y;           // 0..11
    const int t  = threadIdx.x;
    const int b  = qt >> 3;
    const int p0 = (qt & 7) * 128;

    #pragma unroll
    for (int pass = 0; pass < 2; ++pass) {
        int idx = pass * 256 + t;          // bits [rg:2][h2:1][kc:1][r:5]
        int r  = idx & 31;
        int kc = (idx >> 5) & 1;
        int h2 = (idx >> 6) & 1;
        int rg = idx >> 7;
        int prow = rg * 32 + r;
        int kb = g * 64 + kc * 32 + h2 * 16;
        const float* src = emb + ((size_t)b * D + kb) * HW + p0 + prow;
        float v[16];
        float ss = 0.f;
        #pragma unroll
        for (int j = 0; j < 16; ++j) {
            v[j] = src[(size_t)j * HW];
            ss = fmaf(v[j], v[j], ss);
        }
        uint4 o;
        o.x = pack4_fp8(-2.f*v[0],  -2.f*v[1],  -2.f*v[2],  -2.f*v[3]);
        o.y = pack4_fp8(-2.f*v[4],  -2.f*v[5],  -2.f*v[6],  -2.f*v[7]);
        o.z = pack4_fp8(-2.f*v[8],  -2.f*v[9],  -2.f*v[10], -2.f*v[11]);
        o.w = pack4_fp8(-2.f*v[12], -2.f*v[13], -2.f*v[14], -2.f*v[15]);
        qbt8[((size_t)qt * KSTEPS + g) * 512 + idx] = o;
        part[idx] = ss;
    }
    __syncthreads();
    if (t < 128) {
        int base = (t >> 5) * 128 + (t & 31);
        float s = part[base] + part[base + 32] + part[base + 64] + part[base + 96];
        q2p[((size_t)qt * KSTEPS + g) * 128 + t] = s;
    }
}

// ---------------------------------------------------------------------------
// 3) MX-fp8 MFMA GEMM, 256x128 tile, TRIPLE-buffered LDS + register frag
//    double-buffer pipeline. Per step s (one raw s_barrier each):
//      A: issue stage(s+2) -> buf[(s+2)%3]        (6 global_load_lds)
//      B: s_waitcnt vmcnt(6)                      (own stage(s+1) landed)
//      E: s_waitcnt lgkmcnt(0)                    (frags(s) reads done -> WAR-safe)
//      C: s_barrier                               (all stage(s+1) landed)
//      D: issue ds_reads frags(s+1) from buf[(s+1)%3]  (NO wait - fly under F)
//      F: setprio(1); 8 MFMA on frags(s); setprio(0)
//    Hazard ledger:
//      RAW stage->read : B (in-order vmcnt, exactly 6 loads/stage) + C, D after C.
//      WAR read->stage : buf staged at s+2 was last read at s-1; those reads
//                        completed at E before barrier s.C; stage issues after.
//      RAW read->mfma  : E precedes F (sched_barrier pins MFMA below E).
//      x2p loads at tile boundaries sit OLDER in the vm queue than stage(s+2),
//      so vmcnt(6) stays conservative-correct.
//    Tile boundary uses full __syncthreads() (lgkm drain) so the previous
//    epilogue's X2s reads are explicitly ordered before the X2s refill.
__global__ __launch_bounds__(256, 2) void gemm_topk(const unsigned char* __restrict__ dbt8,
                                                    const unsigned char* __restrict__ qbt8,
                                                    const float* __restrict__ x2p,
                                                    float* __restrict__ partials) {
    __shared__ __align__(16) unsigned char Asm[3 * ABUF];   // 48 KB
    __shared__ __align__(16) unsigned char Bsm[3 * BBUF];   // 24 KB
    __shared__ float X2s[BM];                               // 1 KB
    __shared__ float red[4][BN][3];                         // 6 KB   (total 79 KB -> 2 blocks/CU)

    const int tid  = threadIdx.x;
    const int lane = tid & 63;
    const int w    = tid >> 6;           // 0..3
    const int lts  = w >> 1;             // 128-row layout half
    const int wr   = w & 1;
    const int h    = lane >> 5;
    const int l31  = lane & 31;

    const int bid   = blockIdx.x;        // 0..511
    const int xcd   = bid & 7;
    const int j     = bid >> 3;
    const int sp    = xcd + 8 * (j >> 5);   // 0..15
    const int qtile = j & 31;
    const int m0    = qtile * BN;

    // fragment byte offsets within one buffer
    int a_off[2], b_off[4];
    #pragma unroll
    for (int i = 0; i < 2; ++i) a_off[i] = lts * 8192 + (wr * 2 + i) * 2048 + h * 512 + l31 * 16;
    #pragma unroll
    for (int j4 = 0; j4 < 4; ++j4) b_off[j4] = j4 * 2048 + h * 512 + l31 * 16;

    // staging cursors at (tile=sp, g=0); wave w stages A-quarter + B-eighth.
    const unsigned char* aC = dbt8 + (size_t)(2 * sp + lts) * KSTEPS * STEPB + wr * 4096 + lane * 16;
    const unsigned char* bC = qbt8 + (size_t)qtile * KSTEPS * STEPB + w * 2048 + lane * 16;
    int gs = 0;  // g of staging cursor

    auto advance = [&]() {
        if (gs == KSTEPS - 1) {
            aC += (size_t)(2 * NSPLIT) * KSTEPS * STEPB - (size_t)(KSTEPS - 1) * STEPB;
            bC -= (size_t)(KSTEPS - 1) * STEPB;
            gs = 0;
        } else {
            aC += STEPB; bC += STEPB; ++gs;
        }
    };
    auto stage_to = [&](int bi) {
        unsigned char* ad = Asm + bi * ABUF + w * 4096;
        unsigned char* bd = Bsm + bi * BBUF + w * 2048;
        #pragma unroll
        for (int l = 0; l < 4; ++l) gl_lds16(aC + l * 1024, ad + l * 1024);
        #pragma unroll
        for (int l = 0; l < 2; ++l) gl_lds16(bC + l * 1024, bd + l * 1024);
    };
    auto read_frags = [&](int bi, i32x8 (&af)[2], i32x8 (&bf)[4]) {
        const unsigned char* Ab = Asm + bi * ABUF;
        const unsigned char* Bb = Bsm + bi * BBUF;
        #pragma unroll
        for (int i = 0; i < 2; ++i) {
            int4 lo = *(const int4*)(Ab + a_off[i]);
            int4 hi = *(const int4*)(Ab + a_off[i] + 1024);
            af[i] = (i32x8){lo.x, lo.y, lo.z, lo.w, hi.x, hi.y, hi.z, hi.w};
        }
        #pragma unroll
        for (int j4 = 0; j4 < 4; ++j4) {
            int4 lo = *(const int4*)(Bb + b_off[j4]);
            int4 hi = *(const int4*)(Bb + b_off[j4] + 1024);
            bf[j4] = (i32x8){lo.x, lo.y, lo.z, lo.w, hi.x, hi.y, hi.z, hi.w};
        }
    };

    float t0[4], t1[4], t2[4];
    #pragma unroll
    for (int j4 = 0; j4 < 4; ++j4) { t0[j4] = INFINITY; t1[j4] = INFINITY; t2[j4] = INFINITY; }

    f32x16 acc[2][4];

    auto epilogue = [&]() {   // rows = w*64 + i*32 + rg2*8 + 4h + rr
        #pragma unroll
        for (int i = 0; i < 2; ++i) {
            #pragma unroll
            for (int rg2 = 0; rg2 < 4; ++rg2) {
                float4 xv = *(const float4*)&X2s[w * 64 + i * 32 + rg2 * 8 + 4 * h];
                #pragma unroll
                for (int j4 = 0; j4 < 4; ++j4) {
                    #pragma unroll
                    for (int rr = 0; rr < 4; ++rr) {
                        float sv = acc[i][j4][rg2 * 4 + rr] + ((const float*)&xv)[rr];
                        insert3(t0[j4], t1[j4], t2[j4], sv);
                    }
                }
            }
        }
    };
    auto do_mfma = [&](const i32x8 (&af)[2], const i32x8 (&bf)[4]) {
        __builtin_amdgcn_s_setprio(1);
        #pragma unroll
        for (int i = 0; i < 2; ++i)
            #pragma unroll
            for (int j4 = 0; j4 < 4; ++j4)
                acc[i][j4] = __builtin_amdgcn_mfma_scale_f32_32x32x64_f8f6f4(
                    af[i], bf[j4], acc[i][j4], 0, 0,
                    0, 0x7f7f7f7f, 0, 0x7f7f7f7f);
        __builtin_amdgcn_s_setprio(0);
    };

    // tiles handled by this block
    int ntiles = 0;
    for (int t = sp; t < NT2; t += NSPLIT) ++ntiles;
    const int S = ntiles * KSTEPS;       // 48 or 60, multiple of 12 (even)

    // ---- prologue: stage steps 0,1 into buf 0,1; read frags(0)
    stage_to(0); advance();
    stage_to(1); advance();
    asm volatile("s_waitcnt vmcnt(6)" ::: "memory");   // stage(0) landed (own)
    __builtin_amdgcn_s_barrier();                      // all waves' stage(0) landed
    i32x8 afA[2], bfA[4], afB[2], bfB[4];
    read_frags(0, afA, bfA);

    int br = 1;     // buffer holding frags(s+1)
    int bs = 2;     // buffer to stage step s+2 into
    int tile = sp;  // tile whose X2s to fill at next boundary

    for (int s = 0; s < S; s += 2) {
        // ================= even body: compute frags setA (step s) =========
        if ((s % KSTEPS) == 0) {                 // tile boundary (uniform)
            if (s) epilogue();                   // finish previous tile
            __syncthreads();                     // X2s readers done (lgkm drained)
            {   // refill X2s for 'tile' (pad rows -> 1e30)
                int n = tile * BM + tid;
                float xs = 1e30f;
                if (n < NDB) {
                    const float* p = x2p + (size_t)(n >> 7) * (KSTEPS * 128) + (n & 127);
                    xs = 0.f;
                    #pragma unroll
                    for (int g = 0; g < KSTEPS; ++g) xs += p[g * 128];
                }
                X2s[tid] = xs;
            }
            tile += NSPLIT;
            #pragma unroll
            for (int i = 0; i < 2; ++i)
                #pragma unroll
                for (int j4 = 0; j4 < 4; ++j4)
                    #pragma unroll
                    for (int r = 0; r < 16; ++r) acc[i][j4][r] = 0.f;
        }
        if (s + 2 < S) {
            stage_to(bs); advance();
            asm volatile("s_waitcnt vmcnt(6)" ::: "memory");
        } else {
            asm volatile("s_waitcnt vmcnt(0)" ::: "memory");
        }
        asm volatile("s_waitcnt lgkmcnt(0)" ::: "memory");
        __builtin_amdgcn_sched_barrier(0);
        __builtin_amdgcn_s_barrier();
        read_frags(br, afB, bfB);                // frags(s+1), fly under MFMAs
        __builtin_amdgcn_sched_barrier(0);
        do_mfma(afA, bfA);
        bs = (bs == 2) ? 0 : bs + 1;
        br = (br == 2) ? 0 : br + 1;

        // ================= odd body: compute frags setB (step s+1) ========
        if (s + 3 < S) {
            stage_to(bs); advance();
            asm volatile("s_waitcnt vmcnt(6)" ::: "memory");
        } else {
            asm volatile("s_waitcnt vmcnt(0)" ::: "memory");
        }
        asm volatile("s_waitcnt lgkmcnt(0)" ::: "memory");
        __builtin_amdgcn_sched_barrier(0);
        __builtin_amdgcn_s_barrier();
        if (s + 2 < S) read_frags(br, afA, bfA); // frags(s+2)
        __builtin_amdgcn_sched_barrier(0);
        do_mfma(afB, bfB);
        bs = (bs == 2) ? 0 : bs + 1;
        br = (br == 2) ? 0 : br + 1;
    }
    epilogue();   // last tile

    // merge across row-halves (lane^32; col = l31 preserved)
    #pragma unroll
    for (int j4 = 0; j4 < 4; ++j4) {
        float o0 = __shfl_xor(t0[j4], 32);
        float o1 = __shfl_xor(t1[j4], 32);
        float o2 = __shfl_xor(t2[j4], 32);
        insert3(t0[j4], t1[j4], t2[j4], o0);
        insert3(t0[j4], t1[j4], t2[j4], o1);
        insert3(t0[j4], t1[j4], t2[j4], o2);
    }
    if (h == 0) {
        #pragma unroll
        for (int j4 = 0; j4 < 4; ++j4) {
            int col = j4 * 32 + l31;
            red[w][col][0] = t0[j4];
            red[w][col][1] = t1[j4];
            red[w][col][2] = t2[j4];
        }
    }
    __syncthreads();
    if (tid < BN) {
        float a0 = red[0][tid][0], a1 = red[0][tid][1], a2 = red[0][tid][2];
        #pragma unroll
        for (int ww = 1; ww < 4; ++ww) {
            insert3(a0, a1, a2, red[ww][tid][0]);
            insert3(a0, a1, a2, red[ww][tid][1]);
            insert3(a0, a1, a2, red[ww][tid][2]);
        }
        float* dst = partials + ((size_t)(m0 + tid) * NSPLIT + sp) * 3;
        dst[0] = a0; dst[1] = a1; dst[2] = a2;
    }
}

// ---------------------------------------------------------------------------
// 4) merge partials, reduce q2 partials, sqrt, mean
__global__ __launch_bounds__(256) void merge_ood(const float* __restrict__ partials,
                                                 const float* __restrict__ q2p,
                                                 float* __restrict__ ood) {
    int m = blockIdx.x * 256 + threadIdx.x;
    if (m >= M) return;
    const float* pp = partials + (size_t)m * NSPLIT * 3;
    float a0 = INFINITY, a1 = INFINITY, a2 = INFINITY;
    #pragma unroll
    for (int j = 0; j < NSPLIT * 3; ++j) insert3(a0, a1, a2, pp[j]);
    const float* qp = q2p + (size_t)(m >> 7) * KSTEPS * 128 + (m & 127);
    float q = 0.f;
    #pragma unroll
    for (int g = 0; g < KSTEPS; ++g) q += qp[g * 128];
    float d0 = sqrtf(fmaxf(q + a0, 1e-12f));
    float d1 = sqrtf(fmaxf(q + a1, 1e-12f));
    float d2 = sqrtf(fmaxf(q + a2, 1e-12f));
    ood[m] = (d0 + d1 + d2) * (1.f / 3.f);
}

// ---------------------------------------------------------------------------
// 5) half-pixel bilinear 32x32 -> 512x512
__global__ __launch_bounds__(256) void upsample(const float* __restrict__ ood,
                                                float* __restrict__ out) {
    int idx = blockIdx.x * 256 + threadIdx.x;
    int ox = idx & (OUTW - 1);
    int oy = (idx >> 9) & (OUTH - 1);
    int bb = idx >> 18;
    float sx = (ox + 0.5f) * (32.f / OUTW) - 0.5f;
    float sy = (oy + 0.5f) * (32.f / OUTH) - 0.5f;
    float fx = floorf(sx), fy = floorf(sy);
    float wx = sx - fx, wy = sy - fy;
    int x0 = max(0, min(31, (int)fx));
    int x1 = max(0, min(31, (int)fx + 1));
    int y0 = max(0, min(31, (int)fy));
    int y1 = max(0, min(31, (int)fy + 1));
    const float* src = ood + bb * 1024;
    float v00 = src[y0 * 32 + x0];
    float v01 = src[y0 * 32 + x1];
    float v10 = src[y1 * 32 + x0];
    float v11 = src[y1 * 32 + x1];
    float top = v00 + wx * (v01 - v00);
    float bot = v10 + wx * (v11 - v10);
    out[idx] = top + wy * (bot - top);
}

// ---------------------------------------------------------------------------
extern "C" void kernel_launch(void* const* d_in, const int* in_sizes, int n_in,
                              void* d_out, int out_size, void* d_ws, size_t ws_size,
                              hipStream_t stream) {
    const float* emb = (const float*)d_in[0];
    const float* db  = (const float*)d_in[1];
    float* out = (float*)d_out;

    // workspace layout (bytes), total ~20.7 MB
    char* ws = (char*)d_ws;
    unsigned char* dbt8 = (unsigned char*)ws;                    // 158*12*8192 = 15,532,032
    unsigned char* qbt8 = (unsigned char*)(ws + 15532032);       // 32*12*8192  =  3,145,728
    float* x2p      = (float*)(ws + 18677760);                   // 158*12*128*4 = 970,752
    float* q2p      = (float*)(ws + 19648512);                   // 32*12*128*4 = 196,608
    float* ood      = (float*)(ws + 19845120);                   // 16,384
    float* partials = (float*)(ws + 19861504);                   // 4096*16*3*4 = 786,432

    db_convert<<<dim3(LT, KSTEPS), 256, 0, stream>>>(db, (uint4*)dbt8, x2p);
    q_convert<<<dim3(32, KSTEPS), 256, 0, stream>>>(emb, (uint4*)qbt8, q2p);
    gemm_topk<<<NSPLIT * 32, 256, 0, stream>>>(dbt8, qbt8, x2p, partials);
    merge_ood<<<(M + 255) / 256, 256, 0, stream>>>(partials, q2p, ood);
    upsample<<<(B * OUTH * OUTW) / 256, 256, 0, stream>>>(ood, out);
}